// Round 6
// baseline (691.429 us; speedup 1.0000x reference)
//
#include <hip/hip_runtime.h>

#define BB 4096
#define TT 64
#define NH 60
#define KF 7680   // T * 2H
#define NC 600

typedef short bf16x8 __attribute__((ext_vector_type(8)));
typedef float f32x4 __attribute__((ext_vector_type(4)));
#define MFMA16(A,B,C) __builtin_amdgcn_mfma_f32_16x16x32_bf16(A,B,C,0,0,0)

__device__ __forceinline__ unsigned short f2bf(float v) {
    unsigned int u = __float_as_uint(v);
    return (unsigned short)((u + 0x7FFFu + ((u >> 16) & 1u)) >> 16);   // RNE fp32->bf16
}
__device__ __forceinline__ float bf2f(unsigned short b) {
    return __uint_as_float(((unsigned int)b) << 16);
}
__device__ __forceinline__ float sigf(float v)     { return 1.f / (1.f + __expf(-v)); }
__device__ __forceinline__ float tanhfast(float v) { return 2.f / (1.f + __expf(-2.f * v)) - 1.f; }

// unpack 8 packed (hi<<16|lo) u32 -> hi bf16x8, lo bf16x8
__device__ __forceinline__ void unpk(const uint4 a, const uint4 b, bf16x8& hi, bf16x8& lo) {
    uint4 h, l;
    h.x = (a.x >> 16) | (a.y & 0xFFFF0000u);
    h.y = (a.z >> 16) | (a.w & 0xFFFF0000u);
    h.z = (b.x >> 16) | (b.y & 0xFFFF0000u);
    h.w = (b.z >> 16) | (b.w & 0xFFFF0000u);
    l.x = (a.x & 0xFFFFu) | (a.y << 16);
    l.y = (a.z & 0xFFFFu) | (a.w << 16);
    l.z = (b.x & 0xFFFFu) | (b.y << 16);
    l.w = (b.z & 0xFFFFu) | (b.w << 16);
    hi = __builtin_bit_cast(bf16x8, h);
    lo = __builtin_bit_cast(bf16x8, l);
}

// ---------------------------------------------------------------------------
// GRU (gru4, proven 155us): block = 32 rows x 1 dir; 512 thr = 8 waves.
// Double-buffered XH + hstage -> one barrier/step; 6 MFMA chains of 6.
// ---------------------------------------------------------------------------
__global__ __launch_bounds__(512, 2) void gru4_kernel(
    const float* __restrict__ x,      // [B][T][60]
    const float* __restrict__ w_ih,   // [2][180][60]
    const float* __restrict__ w_hh,   // [2][180][60]
    const float* __restrict__ b_ih,   // [2][180]
    const float* __restrict__ b_hh,   // [2][180]
    unsigned int* __restrict__ hs)    // [B][KF] packed (hi<<16 | lo) bf16
{
    __shared__ unsigned short XHh[2][32 * 128];   // 16 KB
    __shared__ unsigned short XHl[2][32 * 128];   // 16 KB
    __shared__ unsigned int hstage[2][32][60];    // 15.4 KB

    const int tid = threadIdx.x;
    const int d  = blockIdx.y;
    const int b0 = blockIdx.x * 32;
    const int wave = tid >> 6, lane = tid & 63;
    const int mtile = wave >> 2, ug = wave & 3;
    const int l15 = lane & 15, lq = lane >> 4;
    const int j = ug * 16 + l15;
    const bool jv = j < NH;
    const int m = mtile * 16 + l15;
    const int rbase = mtile * 16 + lq * 4;

    for (int i = tid; i < 2 * 32 * 128; i += 512) { (&XHh[0][0])[i] = 0; (&XHl[0][0])[i] = 0; }

    bf16x8 wHf[3][4], wLf[3][4];
#pragma unroll
    for (int g = 0; g < 3; ++g) {
#pragma unroll
        for (int kt = 0; kt < 4; ++kt) {
            bf16x8 h8, l8;
            const int kb = kt * 32 + lq * 8;
#pragma unroll
            for (int e = 0; e < 8; ++e) {
                const int k = kb + e;
                float v = 0.f;
                if (jv) {
                    if (k < 60)                    v = w_ih[(size_t)d * 10800 + (g * 60 + j) * 60 + k];
                    else if (k >= 64 && k < 124)   v = w_hh[(size_t)d * 10800 + (g * 60 + j) * 60 + (k - 64)];
                }
                const unsigned short hb = f2bf(v);
                const unsigned short lb = f2bf(v - bf2f(hb));
                h8[e] = (short)hb; l8[e] = (short)lb;
            }
            wHf[g][kt] = h8; wLf[g][kt] = l8;
        }
    }

    float bir = 0, biz = 0, bin = 0, bhr = 0, bhz = 0, bhn = 0;
    if (jv) {
        bir = b_ih[d * 180 + j]; biz = b_ih[d * 180 + 60 + j]; bin = b_ih[d * 180 + 120 + j];
        bhr = b_hh[d * 180 + j]; bhz = b_hh[d * 180 + 60 + j]; bhn = b_hh[d * 180 + 120 + j];
    }

    const bool xact = tid < 480;
    const int rowx = xact ? tid / 15 : 31;
    const int cx   = xact ? tid % 15 : 14;
    const float* xb = x + ((size_t)(b0 + rowx) * TT) * 60 + cx * 4;
    unsigned int* hsb = hs + (size_t)(b0 + rowx) * KF + d * 60 + cx * 4;

    __syncthreads();

    if (xact) {
        const int tt0 = d ? (TT - 1) : 0;
        const float4 v = *(const float4*)(xb + tt0 * 60);
        const float vv[4] = {v.x, v.y, v.z, v.w};
#pragma unroll
        for (int e = 0; e < 4; ++e) {
            const int k = cx * 4 + e;
            const int idx = rowx * 128 + (((k >> 3) ^ (rowx & 7)) << 3) + (k & 7);
            const unsigned short hb = f2bf(vv[e]);
            XHh[0][idx] = hb; XHl[0][idx] = f2bf(vv[e] - bf2f(hb));
        }
    }
    float hold[4] = {0.f, 0.f, 0.f, 0.f};
    __syncthreads();

#pragma unroll 2
    for (int s = 0; s < TT; ++s) {
        const int p = s & 1, pn = p ^ 1;
        const int tt = d ? (TT - 1 - s) : s;

        float4 xp = make_float4(0.f, 0.f, 0.f, 0.f);
        const bool morex = (s < TT - 1) && xact;
        if (morex) xp = *(const float4*)(xb + (d ? (TT - 2 - s) : (s + 1)) * 60);

        f32x4 aR0 = {0,0,0,0}, aR1 = {0,0,0,0}, aZ0 = {0,0,0,0}, aZ1 = {0,0,0,0},
              aNX = {0,0,0,0}, aNH_ = {0,0,0,0};
        const unsigned short* Xh = &XHh[p][0];
        const unsigned short* Xl = &XHl[p][0];
#pragma unroll
        for (int kt = 0; kt < 4; ++kt) {
            const int c = kt * 4 + lq;
            const int off = m * 128 + ((c ^ (m & 7)) << 3);
            const bf16x8 aH = *(const bf16x8*)(Xh + off);
            const bf16x8 aL = *(const bf16x8*)(Xl + off);
            if (kt < 2) {
                aR0 = MFMA16(aH, wHf[0][kt], aR0); aR0 = MFMA16(aH, wLf[0][kt], aR0); aR0 = MFMA16(aL, wHf[0][kt], aR0);
                aZ0 = MFMA16(aH, wHf[1][kt], aZ0); aZ0 = MFMA16(aH, wLf[1][kt], aZ0); aZ0 = MFMA16(aL, wHf[1][kt], aZ0);
                aNX = MFMA16(aH, wHf[2][kt], aNX); aNX = MFMA16(aH, wLf[2][kt], aNX); aNX = MFMA16(aL, wHf[2][kt], aNX);
            } else {
                aR1 = MFMA16(aH, wHf[0][kt], aR1); aR1 = MFMA16(aH, wLf[0][kt], aR1); aR1 = MFMA16(aL, wHf[0][kt], aR1);
                aZ1 = MFMA16(aH, wHf[1][kt], aZ1); aZ1 = MFMA16(aH, wLf[1][kt], aZ1); aZ1 = MFMA16(aL, wHf[1][kt], aZ1);
                aNH_ = MFMA16(aH, wHf[2][kt], aNH_); aNH_ = MFMA16(aH, wLf[2][kt], aNH_); aNH_ = MFMA16(aL, wHf[2][kt], aNH_);
            }
        }

        float hnew[4];
#pragma unroll
        for (int r = 0; r < 4; ++r) {
            const float rr = sigf(aR0[r] + aR1[r] + bir + bhr);
            const float zz = sigf(aZ0[r] + aZ1[r] + biz + bhz);
            const float nn = tanhfast(aNX[r] + bin + rr * (aNH_[r] + bhn));
            hnew[r] = (1.f - zz) * nn + zz * hold[r];
            hold[r] = hnew[r];
        }

        if (jv) {
#pragma unroll
            for (int r = 0; r < 4; ++r) {
                const int rw = rbase + r;
                const int k = 64 + j;
                const int idx = rw * 128 + (((k >> 3) ^ (rw & 7)) << 3) + (k & 7);
                const unsigned short hb = f2bf(hnew[r]);
                const unsigned short lb = f2bf(hnew[r] - bf2f(hb));
                XHh[pn][idx] = hb; XHl[pn][idx] = lb;
                hstage[pn][rw][j] = ((unsigned int)hb << 16) | lb;
            }
        }
        if (morex) {
            const float vv[4] = {xp.x, xp.y, xp.z, xp.w};
#pragma unroll
            for (int e = 0; e < 4; ++e) {
                const int k = cx * 4 + e;
                const int idx = rowx * 128 + (((k >> 3) ^ (rowx & 7)) << 3) + (k & 7);
                const unsigned short hb = f2bf(vv[e]);
                XHh[pn][idx] = hb; XHl[pn][idx] = f2bf(vv[e] - bf2f(hb));
            }
        }
        __syncthreads();

        if (xact) {
            const uint4 hv = *(const uint4*)&hstage[pn][rowx][cx * 4];
            *(uint4*)(hsb + (size_t)tt * 120) = hv;
        }
    }
}

// out[b][c] = fcb[c]  (bias init; FC atomically accumulates on top)
__global__ void out_init_kernel(const float* __restrict__ fcb, float* __restrict__ out) {
    const int i = blockIdx.x * 1024 + threadIdx.x;
    out[i] = fcb[i % NC];
}

// ---------------------------------------------------------------------------
// FC round-6: 128M x 128N x BK32, 256 thr = 4 waves (2m x 2n, 64x64 wave-tile).
// 64 KB LDS -> 2 blocks/CU (cross-block latency hiding). 2-term split.
// A: packed u32, 128B rows, 8-chunk XOR swizzle (fc5-proven, conflict-free),
//    half-buffers A0/A1 alternate per BK32 phase.
// B: bf16, staged at BK=64 macro (128B rows, 8-chunk swizzle, conflict-free),
//    double-buffered per macro.
// Reg-staging, 2-phase load->use gap, lgkm-only barriers (no vmcnt drain).
// kz=3 (K chunk 2560 = 40 macros), epilogue atomicAdd.
// ---------------------------------------------------------------------------
__global__ __launch_bounds__(256, 2) void fc6_kernel(
    const unsigned int* __restrict__ hs,  // [B][KF] packed
    const float* __restrict__ fcw,        // [600][KF]
    float* __restrict__ out)              // [B][600]
{
    __shared__ unsigned int  A0[128 * 32];        // 16 KB (even BK32 halves)
    __shared__ unsigned int  A1[128 * 32];        // 16 KB (odd halves)
    __shared__ unsigned short Bsm[2][128 * 64];   // 16 KB each

    const int tid = threadIdx.x;
    const int m0 = blockIdx.x * 128;
    const int n0 = blockIdx.y * 128;
    const int k0 = blockIdx.z * 2560;
    const int wave = tid >> 6, lane = tid & 63;
    const int wm = wave >> 1, wn = wave & 1;
    const int l15 = lane & 15, lq = lane >> 4;

    // staging map: thread owns chunk-column sc (const), rows srow + it*16
    const int srow = tid >> 4;          // 0..15
    const int sc   = tid & 15;          // 0..15 (A: uint4 chunk; B: float4 chunk)
    const bool hA1 = sc >= 8;           // stages odd half of A
    const int ci   = sc & 7;            // in-half chunk index

    f32x4 acc[4][4];
#pragma unroll
    for (int a = 0; a < 4; ++a)
#pragma unroll
        for (int b = 0; b < 4; ++b) acc[a][b] = (f32x4){0, 0, 0, 0};

    uint4 pa[8]; float4 pb[8];

#define LOAD_A(kc_) do {                                                            \
    _Pragma("unroll")                                                               \
    for (int it = 0; it < 8; ++it) {                                                \
        const int row_ = srow + it * 16;                                            \
        pa[it] = *(const uint4*)(hs + (size_t)(m0 + row_) * KF + (kc_) + sc * 4);   \
    }                                                                               \
} while (0)

#define WRITE_A(ap_) do {                                                           \
    _Pragma("unroll")                                                               \
    for (int it = 0; it < 8; ++it) {                                                \
        const int row_ = srow + it * 16;                                            \
        *(uint4*)((ap_) + row_ * 32 + ((ci ^ (row_ & 7)) << 2)) = pa[it];           \
    }                                                                               \
} while (0)

#define LOAD_B(kc_) do {                                                            \
    _Pragma("unroll")                                                               \
    for (int it = 0; it < 8; ++it) {                                                \
        const int row_ = srow + it * 16;                                            \
        const int cc_ = n0 + row_;                                                  \
        pb[it] = (cc_ < NC) ? *(const float4*)(fcw + (size_t)cc_ * KF + (kc_) + sc * 4) \
                            : make_float4(0.f, 0.f, 0.f, 0.f);                      \
    }                                                                               \
} while (0)

#define WRITE_B(bp_) do {                                                           \
    _Pragma("unroll")                                                               \
    for (int it = 0; it < 8; ++it) {                                                \
        const int row_ = srow + it * 16;                                            \
        const unsigned short h0_ = f2bf(pb[it].x), h1_ = f2bf(pb[it].y);            \
        const unsigned short h2_ = f2bf(pb[it].z), h3_ = f2bf(pb[it].w);            \
        uint2 wv_;                                                                  \
        wv_.x = (unsigned int)h0_ | ((unsigned int)h1_ << 16);                      \
        wv_.y = (unsigned int)h2_ | ((unsigned int)h3_ << 16);                      \
        *(uint2*)((bp_) + row_ * 64 + (((sc >> 1) ^ (row_ & 7)) << 3) + (sc & 1) * 4) = wv_; \
    }                                                                               \
} while (0)

#define MFMA_PH(ha_, bb_, kt_) do {                                                 \
    bf16x8 aH_[4], aL_[4], bF_[4];                                                  \
    _Pragma("unroll")                                                               \
    for (int t_ = 0; t_ < 4; ++t_) {                                                \
        const int mr_ = wm * 64 + t_ * 16 + l15;                                    \
        const unsigned int* pr_ = (ha_) + mr_ * 32;                                 \
        const uint4 c0_ = *(const uint4*)(pr_ + (((2 * lq) ^ (mr_ & 7)) << 2));     \
        const uint4 c1_ = *(const uint4*)(pr_ + (((2 * lq + 1) ^ (mr_ & 7)) << 2)); \
        unpk(c0_, c1_, aH_[t_], aL_[t_]);                                           \
        const int nr_ = wn * 64 + t_ * 16 + l15;                                    \
        bF_[t_] = *(const bf16x8*)((bb_) + nr_ * 64 + ((((kt_) * 4 + lq) ^ (nr_ & 7)) << 3)); \
    }                                                                               \
    _Pragma("unroll")                                                               \
    for (int mt_ = 0; mt_ < 4; ++mt_)                                               \
        _Pragma("unroll")                                                           \
        for (int nt_ = 0; nt_ < 4; ++nt_) {                                         \
            acc[mt_][nt_] = MFMA16(aH_[mt_], bF_[nt_], acc[mt_][nt_]);              \
            acc[mt_][nt_] = MFMA16(aL_[mt_], bF_[nt_], acc[mt_][nt_]);              \
        }                                                                           \
} while (0)

#define LGKM_BAR() do {                                                             \
    asm volatile("s_waitcnt lgkmcnt(0)" ::: "memory");                              \
    __builtin_amdgcn_s_barrier();                                                   \
    __builtin_amdgcn_sched_barrier(0);                                              \
} while (0)

    // ---- prologue: stage macro 0 fully; preload next for h0-threads and B ----
    LOAD_A(k0);
    LOAD_B(k0);
    if (!hA1) WRITE_A(A0);        // h0 -> A0 (c<8 threads; c>=8 HOLD pa = A(0,h1))
    WRITE_B(&Bsm[0][0]);
    if (!hA1) LOAD_A(k0 + 64);    // A(1,h0)
    LOAD_B(k0 + 64);              // B(1)
    LGKM_BAR();

#pragma unroll 1
    for (int T = 0; T < 40; ++T) {
        const int bm = T & 1;
        const unsigned short* Bcur = &Bsm[bm][0];
        unsigned short* Bnxt = &Bsm[bm ^ 1][0];
        const int kc1 = k0 + (T + 1 < 40 ? T + 1 : 39) * 64;
        const int kc2 = k0 + (T + 2 < 40 ? (T + 2 < 40 ? T + 2 : 39) : 39) * 64;

        // phase 0: compute (A0, kt=0); h1-threads stage A(T,h1) and load A(T+1,h1)
        if (hA1) WRITE_A(A1);
        if (hA1) LOAD_A(kc1);
        MFMA_PH(A0, Bcur, 0);
        LGKM_BAR();

        // phase 1: compute (A1, kt=1); h0-threads stage A(T+1,h0), all stage B(T+1)
        if (!hA1) WRITE_A(A0);
        WRITE_B(Bnxt);
        if (!hA1) LOAD_A(kc2);
        LOAD_B(kc2);
        MFMA_PH(A1, Bcur, 1);
        LGKM_BAR();
    }

    // ---- epilogue: atomic accumulate (kz=3 chunks per out element) ----
#pragma unroll
    for (int mt = 0; mt < 4; ++mt) {
        const int row = m0 + wm * 64 + mt * 16 + lq * 4;
#pragma unroll
        for (int nt = 0; nt < 4; ++nt) {
            const int col = n0 + wn * 64 + nt * 16 + l15;
            if (col < NC) {
#pragma unroll
                for (int r = 0; r < 4; ++r)
                    atomicAdd(out + (size_t)(row + r) * NC + col, acc[mt][nt][r]);
            }
        }
    }
#undef LOAD_A
#undef WRITE_A
#undef LOAD_B
#undef WRITE_B
#undef MFMA_PH
#undef LGKM_BAR
}

extern "C" void kernel_launch(void* const* d_in, const int* in_sizes, int n_in,
                              void* d_out, int out_size, void* d_ws, size_t ws_size,
                              hipStream_t stream) {
    (void)in_sizes; (void)n_in; (void)out_size;
    const float* x    = (const float*)d_in[0];
    const float* w_ih = (const float*)d_in[1];
    const float* w_hh = (const float*)d_in[2];
    const float* b_ih = (const float*)d_in[3];
    const float* b_hh = (const float*)d_in[4];
    const float* fcw  = (const float*)d_in[5];
    const float* fcb  = (const float*)d_in[6];
    float* out = (float*)d_out;
    unsigned int* hs = (unsigned int*)d_ws;          // [B][KF] packed bf16 hi/lo = 125.8 MB

    if (ws_size < (size_t)KF * BB * sizeof(unsigned int)) return;

    out_init_kernel<<<dim3((BB * NC) / 1024), 1024, 0, stream>>>(fcb, out);
    gru4_kernel<<<dim3(BB / 32, 2), 512, 0, stream>>>(x, w_ih, w_hh, b_ih, b_hh, hs);
    fc6_kernel<<<dim3(BB / 128, 5, 3), 256, 0, stream>>>(hs, fcw, out);
}